// Round 4
// baseline (556.233 us; speedup 1.0000x reference)
//
#include <hip/hip_runtime.h>
#include <hip/hip_bf16.h>

typedef __bf16 bf16x8_t __attribute__((ext_vector_type(8)));
typedef float f32x4_t __attribute__((ext_vector_type(4)));

__device__ __forceinline__ float bits2f(unsigned int u) {
    union { unsigned int u; float f; } c; c.u = u; return c.f;
}
__device__ __forceinline__ unsigned short f2bf_bits(float f) {
    __hip_bfloat16 h = __float2bfloat16(f);
    return __builtin_bit_cast(unsigned short, h);
}

// ---------------- sentinel (ws too small) ----------------
__global__ void sentinel_fill(float* __restrict__ out, int n) {
    int i = blockIdx.x * blockDim.x + threadIdx.x;
    if (i < n) out[i] = 100.0f;
}

// ---------------- edge_index dtype detection (int64 vs int32) ----------------
__global__ void detect_ei(const unsigned int* __restrict__ ei, int* __restrict__ flags) {
    int lane = threadIdx.x;
    int cz = 0;
    #pragma unroll
    for (int j = 0; j < 4; ++j) {
        int idx = lane * 4 + j;          // 0..255
        cz += (ei[2 * idx + 1] == 0u);   // odd words zero => int64 storage
    }
    #pragma unroll
    for (int off = 32; off; off >>= 1) cz += __shfl_down(cz, off);
    if (lane == 0) flags[0] = (cz > 200);
}

// ---------------- CSR build (dual i32/i64 edge reads) ----------------

__global__ void count_edges_dual(const int* __restrict__ ei, int* __restrict__ cnt,
                                 int E, int M, const int* __restrict__ flags) {
    int e = blockIdx.x * blockDim.x + threadIdx.x;
    if (e < E) {
        int c = flags[0] ? ei[2 * E + 2 * e] : ei[E + e];
        if ((unsigned)c < (unsigned)M) atomicAdd(&cnt[c], 1);
    }
}

__global__ void compute_dinv(const int* __restrict__ cnt, float* __restrict__ dinv, int M) {
    int i = blockIdx.x * blockDim.x + threadIdx.x;
    if (i < M) dinv[i] = rsqrtf((float)cnt[i] + 1.0f);
}

// single-block scan: 1024 threads, wave-level shuffles + per-chunk carry
__global__ void scan_kernel(const int* __restrict__ cnt, int* __restrict__ colptr,
                            int* __restrict__ cursor, int n) {
    const int tid = threadIdx.x;
    const int lane = tid & 63;
    const int wv = tid >> 6;          // 16 waves
    __shared__ int wsum[16];
    __shared__ int carry_s;
    if (tid == 0) carry_s = 0;
    __syncthreads();
    for (int base = 0; base < n; base += 1024) {
        int i = base + tid;
        int v = (i < n) ? cnt[i] : 0;
        int s = v;
        #pragma unroll
        for (int off = 1; off < 64; off <<= 1) {
            int t = __shfl_up(s, off);
            if (lane >= off) s += t;
        }
        if (lane == 63) wsum[wv] = s;
        __syncthreads();
        if (wv == 0) {
            int ws = (lane < 16) ? wsum[lane] : 0;
            #pragma unroll
            for (int off = 1; off < 16; off <<= 1) {
                int t = __shfl_up(ws, off);
                if (lane >= off) ws += t;
            }
            if (lane < 16) wsum[lane] = ws;
        }
        __syncthreads();
        int wave_excl = (wv == 0) ? 0 : wsum[wv - 1];
        int incl = s + wave_excl + carry_s;
        if (i < n) { colptr[i] = incl - v; cursor[i] = incl - v; }
        __syncthreads();
        if (tid == 1023) carry_s = incl;
        __syncthreads();
    }
    if (tid == 0) colptr[n] = carry_s;
}

__global__ void fill_csr_dual(const int* __restrict__ ei, int* __restrict__ cursor,
                              int* __restrict__ esrc, int E, int M,
                              const int* __restrict__ flags) {
    int e = blockIdx.x * blockDim.x + threadIdx.x;
    if (e < E) {
        int r, c;
        if (flags[0]) { r = ei[2 * e]; c = ei[2 * E + 2 * e]; }
        else          { r = ei[e];     c = ei[E + e]; }
        if ((unsigned)c < (unsigned)M && (unsigned)r < (unsigned)M) {
            int p = atomicAdd(&cursor[c], 1);
            if ((unsigned)p < (unsigned)E) esrc[p] = r;
        }
    }
}

// ---------------- weight transpose f32 -> bf16 ----------------
__global__ void transpose_w(const float* __restrict__ in, unsigned short* __restrict__ out,
                            int K, int N) {
    int i = blockIdx.x * blockDim.x + threadIdx.x;
    if (i < K * N) {
        int k = i / N, n = i - k * N;
        out[(size_t)n * K + k] = f2bf_bits(in[i]);
    }
}

// ---------------- GEMM + dinv scale (bf16 MFMA) ----------------
// Y[m][n] = dinv[m] * sum_k A[m][k] * W[k][n],  Bt = W^T ([N][K] row-major, bf16)
// AF32: A stored as f32 (layer 1 input x); else bf16.
template<int K, int N, bool AF32>
__global__ __launch_bounds__(256) void gemm_scale(
    const void* __restrict__ A,
    const __hip_bfloat16* __restrict__ Bt,
    const float* __restrict__ dinv,
    __hip_bfloat16* __restrict__ Y,
    int M)
{
    const int lane = threadIdx.x & 63;
    const int wave = threadIdx.x >> 6;   // 4 waves, 16 rows each
    const int quad = lane >> 4;          // 0..3
    const int l16  = lane & 15;

    int mload = blockIdx.x * 64 + wave * 16 + l16;
    if (mload >= M) mload = M - 1;

    const __bf16* Ab = (const __bf16*)A + (size_t)mload * K + quad * 8;
    const float*  Af = (const float*)A + (size_t)mload * K + quad * 8;
    const __bf16* Bp = (const __bf16*)Bt + (size_t)l16 * K + quad * 8;

    f32x4_t acc[N / 16];
#pragma unroll
    for (int t = 0; t < N / 16; ++t) acc[t] = (f32x4_t){0.f, 0.f, 0.f, 0.f};

    for (int kc = 0; kc < K; kc += 32) {
        bf16x8_t af;
        if constexpr (AF32) {
            float4 f0 = *(const float4*)(Af + kc);
            float4 f1 = *(const float4*)(Af + kc + 4);
            af = (bf16x8_t){(__bf16)f0.x, (__bf16)f0.y, (__bf16)f0.z, (__bf16)f0.w,
                            (__bf16)f1.x, (__bf16)f1.y, (__bf16)f1.z, (__bf16)f1.w};
        } else {
            af = *(const bf16x8_t*)(Ab + kc);
        }
#pragma unroll
        for (int t = 0; t < N / 16; ++t) {
            bf16x8_t bfr = *(const bf16x8_t*)(Bp + (size_t)t * 16 * K + kc);
            acc[t] = __builtin_amdgcn_mfma_f32_16x16x32_bf16(af, bfr, acc[t], 0, 0, 0);
        }
    }

    // D: lane holds rows quad*4+r (r=0..3), col l16 (per 16-wide tile)
    int rowbase = blockIdx.x * 64 + wave * 16 + quad * 4;
#pragma unroll
    for (int r = 0; r < 4; ++r) {
        int rrow = rowbase + r;
        if (rrow < M) {
            float dv = dinv[rrow];
#pragma unroll
            for (int t = 0; t < N / 16; ++t) {
                Y[(size_t)rrow * N + t * 16 + l16] = __float2bfloat16(acc[t][r] * dv);
            }
        }
    }
}

// ---------------- Aggregation: out[i] = act(dinv[i]*(sum y[src] + y[i]) + b) ----------------
// bias read as f32. OUTF32: write f32 (final layer) else bf16 (hidden layers).
template<int C, bool SIG, bool OUTF32>
__global__ __launch_bounds__(256) void aggregate(
    const __hip_bfloat16* __restrict__ Y,
    const int* __restrict__ colptr,
    const int* __restrict__ esrc,
    const float* __restrict__ dinv,
    const float* __restrict__ bias,
    void* __restrict__ H,
    int M, int Etot)
{
    const int lane = threadIdx.x & 63;
    const int wave = threadIdx.x >> 6;
    int node = blockIdx.x * 4 + wave;
    if (node >= M) return;

    const unsigned short* Yp = (const unsigned short*)Y;
    int s = colptr[node];
    int e = colptr[node + 1];
    if (s < 0) s = 0;
    if (e > Etot) e = Etot;
    if (e < s) e = s;

    float a0 = 0.f, a1 = 0.f, a2 = 0.f, a3 = 0.f;

    for (int base = s; base < e; base += 64) {
        int n = e - base; if (n > 64) n = 64;
        int my = (lane < n) ? esrc[base + lane] : 0;
        if ((unsigned)my >= (unsigned)M) my = 0;
        for (int j = 0; j < n; ++j) {
            int src = __shfl(my, j);
            if constexpr (C == 256) {
                uint2 u = *(const uint2*)(Yp + (size_t)src * C + lane * 4);
                a0 += bits2f(u.x << 16);
                a1 += bits2f(u.x & 0xffff0000u);
                a2 += bits2f(u.y << 16);
                a3 += bits2f(u.y & 0xffff0000u);
            } else {
                unsigned int u = Yp[(size_t)src * C + lane];
                a0 += bits2f(u << 16);
            }
        }
    }
    // self-loop term
    if constexpr (C == 256) {
        uint2 u = *(const uint2*)(Yp + (size_t)node * C + lane * 4);
        a0 += bits2f(u.x << 16);
        a1 += bits2f(u.x & 0xffff0000u);
        a2 += bits2f(u.y << 16);
        a3 += bits2f(u.y & 0xffff0000u);
    } else {
        unsigned int u = Yp[(size_t)node * C + lane];
        a0 += bits2f(u << 16);
    }

    float dv = dinv[node];
    if constexpr (C == 256) {
        float o0 = a0 * dv + bias[lane * 4 + 0];
        float o1 = a1 * dv + bias[lane * 4 + 1];
        float o2 = a2 * dv + bias[lane * 4 + 2];
        float o3 = a3 * dv + bias[lane * 4 + 3];
        if (SIG) {
            o0 = 1.f / (1.f + __expf(-o0));
            o1 = 1.f / (1.f + __expf(-o1));
            o2 = 1.f / (1.f + __expf(-o2));
            o3 = 1.f / (1.f + __expf(-o3));
        }
        if constexpr (OUTF32) {
            float4 st = {o0, o1, o2, o3};
            *(float4*)((float*)H + (size_t)node * C + lane * 4) = st;
        } else {
            unsigned int p0 = (unsigned int)f2bf_bits(o0) | ((unsigned int)f2bf_bits(o1) << 16);
            unsigned int p1 = (unsigned int)f2bf_bits(o2) | ((unsigned int)f2bf_bits(o3) << 16);
            uint2 st; st.x = p0; st.y = p1;
            *(uint2*)((unsigned short*)H + (size_t)node * C + lane * 4) = st;
        }
    } else {
        float o = a0 * dv + bias[lane];
        if (SIG) o = 1.f / (1.f + __expf(-o));
        if constexpr (OUTF32) {
            ((float*)H)[(size_t)node * C + lane] = o;
        } else {
            ((unsigned short*)H)[(size_t)node * C + lane] = f2bf_bits(o);
        }
    }
}

// ---------------- launch ----------------

extern "C" void kernel_launch(void* const* d_in, const int* in_sizes, int n_in,
                              void* d_out, int out_size, void* d_ws, size_t ws_size,
                              hipStream_t stream)
{
    // Input order per setup_inputs(): x, edge_attr, edge_index, W1,b1,W2,b2,W3,b3.
    int iEI = 2, iW1 = 3, iB1 = 4, iW2 = 5, iB2 = 6, iW3 = 7, iB3 = 8;
    if (n_in == 8) { iEI = 1; iW1 = 2; iB1 = 3; iW2 = 4; iB2 = 5; iW3 = 6; iB3 = 7; }

    const void* x   = d_in[0];
    const int* ei   = (const int*)d_in[iEI];
    const float* W1 = (const float*)d_in[iW1];
    const float* b1 = (const float*)d_in[iB1];
    const float* W2 = (const float*)d_in[iW2];
    const float* b2 = (const float*)d_in[iB2];
    const float* W3 = (const float*)d_in[iW3];
    const float* b3 = (const float*)d_in[iB3];

    const int M = in_sizes[0] / 128;     // 50000
    const int E = in_sizes[iEI] / 2;     // 800000

    auto rnd = [](size_t b) { return (b + 255) & ~(size_t)255; };
    size_t needed = rnd(64 * 4)                          // flags
                  + rnd((size_t)M * 4) * 2               // dinv, cnt
                  + rnd((size_t)(M + 1) * 4)             // colptr
                  + rnd((size_t)M * 4)                   // cursor
                  + rnd((size_t)E * 4)                   // esrc
                  + rnd((size_t)256 * 128 * 2)           // Wt1
                  + rnd((size_t)256 * 256 * 2)           // Wt2
                  + rnd((size_t)64 * 256 * 2)            // Wt3
                  + rnd((size_t)M * 256 * 2) * 2;        // ybuf, hbuf
    if (ws_size < needed) {
        sentinel_fill<<<(out_size + 255) / 256, 256, 0, stream>>>((float*)d_out, out_size);
        return;
    }

    char* p = (char*)d_ws;
    auto alloc = [&](size_t bytes) {
        char* r = p;
        p += (bytes + 255) & ~(size_t)255;
        return r;
    };
    int* flags  = (int*)alloc(64 * 4);
    float* dinv = (float*)alloc((size_t)M * 4);
    int* cnt    = (int*)alloc((size_t)M * 4);
    int* colptr = (int*)alloc((size_t)(M + 1) * 4);
    int* cursor = (int*)alloc((size_t)M * 4);
    int* esrc   = (int*)alloc((size_t)E * 4);
    unsigned short* Wt1 = (unsigned short*)alloc((size_t)256 * 128 * 2);
    unsigned short* Wt2 = (unsigned short*)alloc((size_t)256 * 256 * 2);
    unsigned short* Wt3 = (unsigned short*)alloc((size_t)64 * 256 * 2);
    __hip_bfloat16* ybuf = (__hip_bfloat16*)alloc((size_t)M * 256 * 2);
    __hip_bfloat16* hbuf = (__hip_bfloat16*)alloc((size_t)M * 256 * 2);

    detect_ei<<<1, 64, 0, stream>>>((const unsigned int*)ei, flags);

    hipMemsetAsync(cnt, 0, (size_t)M * 4, stream);
    count_edges_dual<<<(E + 255) / 256, 256, 0, stream>>>(ei, cnt, E, M, flags);
    compute_dinv<<<(M + 255) / 256, 256, 0, stream>>>(cnt, dinv, M);
    scan_kernel<<<1, 1024, 0, stream>>>(cnt, colptr, cursor, M);
    fill_csr_dual<<<(E + 255) / 256, 256, 0, stream>>>(ei, cursor, esrc, E, M, flags);
    transpose_w<<<(128 * 256 + 255) / 256, 256, 0, stream>>>(W1, Wt1, 128, 256);
    transpose_w<<<(256 * 256 + 255) / 256, 256, 0, stream>>>(W2, Wt2, 256, 256);
    transpose_w<<<(256 * 64 + 255) / 256, 256, 0, stream>>>(W3, Wt3, 256, 64);

    int gb = (M + 63) / 64;
    int ga = (M + 3) / 4;
    gemm_scale<128, 256, true><<<gb, 256, 0, stream>>>(x, (const __hip_bfloat16*)Wt1, dinv, ybuf, M);
    aggregate<256, true, false><<<ga, 256, 0, stream>>>(ybuf, colptr, esrc, dinv, b1, hbuf, M, E);
    gemm_scale<256, 256, false><<<gb, 256, 0, stream>>>(hbuf, (const __hip_bfloat16*)Wt2, dinv, ybuf, M);
    aggregate<256, true, false><<<ga, 256, 0, stream>>>(ybuf, colptr, esrc, dinv, b2, hbuf, M, E);
    gemm_scale<256, 64, false><<<gb, 256, 0, stream>>>(hbuf, (const __hip_bfloat16*)Wt3, dinv, ybuf, M);
    aggregate<64, false, true><<<ga, 256, 0, stream>>>(ybuf, colptr, esrc, dinv, b3, d_out, M, E);
}

// Round 5
// 505.305 us; speedup vs baseline: 1.1008x; 1.1008x over previous
//
#include <hip/hip_runtime.h>
#include <hip/hip_bf16.h>

typedef __bf16 bf16x8_t __attribute__((ext_vector_type(8)));
typedef float f32x4_t __attribute__((ext_vector_type(4)));

__device__ __forceinline__ float bits2f(unsigned int u) {
    union { unsigned int u; float f; } c; c.u = u; return c.f;
}
__device__ __forceinline__ unsigned short f2bf_bits(float f) {
    __hip_bfloat16 h = __float2bfloat16(f);
    return __builtin_bit_cast(unsigned short, h);
}

// ---------------- sentinel (ws too small) ----------------
__global__ void sentinel_fill(float* __restrict__ out, int n) {
    int i = blockIdx.x * blockDim.x + threadIdx.x;
    if (i < n) out[i] = 100.0f;
}

// ---------------- edge_index dtype detection (int64 vs int32) ----------------
__global__ void detect_ei(const unsigned int* __restrict__ ei, int* __restrict__ flags) {
    int lane = threadIdx.x;
    int cz = 0;
    #pragma unroll
    for (int j = 0; j < 4; ++j) {
        int idx = lane * 4 + j;          // 0..255
        cz += (ei[2 * idx + 1] == 0u);   // odd words zero => int64 storage
    }
    #pragma unroll
    for (int off = 32; off; off >>= 1) cz += __shfl_down(cz, off);
    if (lane == 0) flags[0] = (cz > 200);
}

// ---------------- CSR build (dual i32/i64 edge reads) ----------------

__global__ void count_edges_dual(const int* __restrict__ ei, int* __restrict__ cnt,
                                 int E, int M, const int* __restrict__ flags) {
    int e = blockIdx.x * blockDim.x + threadIdx.x;
    if (e < E) {
        int c = flags[0] ? ei[2 * E + 2 * e] : ei[E + e];
        if ((unsigned)c < (unsigned)M) atomicAdd(&cnt[c], 1);
    }
}

__global__ void compute_dinv(const int* __restrict__ cnt, float* __restrict__ dinv, int M) {
    int i = blockIdx.x * blockDim.x + threadIdx.x;
    if (i < M) dinv[i] = rsqrtf((float)cnt[i] + 1.0f);
}

// single-block scan: 1024 threads, wave-level shuffles + per-chunk carry
__global__ void scan_kernel(const int* __restrict__ cnt, int* __restrict__ colptr,
                            int* __restrict__ cursor, int n) {
    const int tid = threadIdx.x;
    const int lane = tid & 63;
    const int wv = tid >> 6;          // 16 waves
    __shared__ int wsum[16];
    __shared__ int carry_s;
    if (tid == 0) carry_s = 0;
    __syncthreads();
    for (int base = 0; base < n; base += 1024) {
        int i = base + tid;
        int v = (i < n) ? cnt[i] : 0;
        int s = v;
        #pragma unroll
        for (int off = 1; off < 64; off <<= 1) {
            int t = __shfl_up(s, off);
            if (lane >= off) s += t;
        }
        if (lane == 63) wsum[wv] = s;
        __syncthreads();
        if (wv == 0) {
            int ws = (lane < 16) ? wsum[lane] : 0;
            #pragma unroll
            for (int off = 1; off < 16; off <<= 1) {
                int t = __shfl_up(ws, off);
                if (lane >= off) ws += t;
            }
            if (lane < 16) wsum[lane] = ws;
        }
        __syncthreads();
        int wave_excl = (wv == 0) ? 0 : wsum[wv - 1];
        int incl = s + wave_excl + carry_s;
        if (i < n) { colptr[i] = incl - v; cursor[i] = incl - v; }
        __syncthreads();
        if (tid == 1023) carry_s = incl;
        __syncthreads();
    }
    if (tid == 0) colptr[n] = carry_s;
}

__global__ void fill_csr_dual(const int* __restrict__ ei, int* __restrict__ cursor,
                              int* __restrict__ esrc, int E, int M,
                              const int* __restrict__ flags) {
    int e = blockIdx.x * blockDim.x + threadIdx.x;
    if (e < E) {
        int r, c;
        if (flags[0]) { r = ei[2 * e]; c = ei[2 * E + 2 * e]; }
        else          { r = ei[e];     c = ei[E + e]; }
        if ((unsigned)c < (unsigned)M && (unsigned)r < (unsigned)M) {
            int p = atomicAdd(&cursor[c], 1);
            if ((unsigned)p < (unsigned)E) esrc[p] = r;
        }
    }
}

// ---------------- weight transpose f32 -> bf16 ----------------
__global__ void transpose_w(const float* __restrict__ in, unsigned short* __restrict__ out,
                            int K, int N) {
    int i = blockIdx.x * blockDim.x + threadIdx.x;
    if (i < K * N) {
        int k = i / N, n = i - k * N;
        out[(size_t)n * K + k] = f2bf_bits(in[i]);
    }
}

// ---------------- tiled GEMM + dinv scale (bf16 MFMA) ----------------
// Y[m][n0+n] = dinv[m] * sum_k A[m][k] * Bt[n0+n][k]
// Block: 4 waves (2x2) over a 128 x BN tile; wave tile 64 x (BN/2).
// B tile staged once in LDS (K+8 pad). NTOT = full output width (Y stride).
template<int K, int BN, int NTOT, bool AF32>
__global__ __launch_bounds__(256) void gemm_tile(
    const void* __restrict__ A,
    const unsigned short* __restrict__ Bt,
    const float* __restrict__ dinv,
    __hip_bfloat16* __restrict__ Y,
    int M)
{
    constexpr int KP = K + 8;
    constexpr int NT = BN / 2 / 16;   // n-tiles per wave
    __shared__ unsigned short Bs[BN * KP];

    const int tid  = threadIdx.x;
    const int lane = tid & 63;
    const int wave = tid >> 6;        // 0..3
    const int wm   = wave >> 1;       // 0..1  row group
    const int wn   = wave & 1;        // 0..1  col group
    const int quad = lane >> 4;       // 0..3
    const int l16  = lane & 15;
    const int n0   = blockIdx.y * BN;

    // ---- stage B tile into LDS (one shot) ----
    constexpr int CH = BN * K / 8;    // 16B chunks
    for (int idx = tid; idx < CH; idx += 256) {
        int n  = idx / (K / 8);
        int k8 = idx - n * (K / 8);
        uint4 v = *(const uint4*)(Bt + (size_t)(n0 + n) * K + k8 * 8);
        *(uint4*)&Bs[n * KP + k8 * 8] = v;
    }
    __syncthreads();

    // ---- A row indices (clamped for loads) ----
    int mrow[4];
#pragma unroll
    for (int mt = 0; mt < 4; ++mt) {
        int r = blockIdx.x * 128 + wm * 64 + mt * 16 + l16;
        mrow[mt] = (r < M) ? r : (M - 1);
    }

    f32x4_t acc[4][NT];
#pragma unroll
    for (int mt = 0; mt < 4; ++mt)
#pragma unroll
        for (int t = 0; t < NT; ++t) acc[mt][t] = (f32x4_t){0.f, 0.f, 0.f, 0.f};

    const unsigned short* BsW = &Bs[(wn * (BN / 2)) * KP];

#pragma unroll
    for (int kc = 0; kc < K; kc += 32) {
        bf16x8_t a[4], b[NT];
#pragma unroll
        for (int mt = 0; mt < 4; ++mt) {
            if constexpr (AF32) {
                const float* Af = (const float*)A + (size_t)mrow[mt] * K + kc + quad * 8;
                float4 f0 = *(const float4*)(Af);
                float4 f1 = *(const float4*)(Af + 4);
                a[mt] = (bf16x8_t){(__bf16)f0.x, (__bf16)f0.y, (__bf16)f0.z, (__bf16)f0.w,
                                   (__bf16)f1.x, (__bf16)f1.y, (__bf16)f1.z, (__bf16)f1.w};
            } else {
                a[mt] = *(const bf16x8_t*)((const __bf16*)A + (size_t)mrow[mt] * K + kc + quad * 8);
            }
        }
#pragma unroll
        for (int t = 0; t < NT; ++t) {
            b[t] = *(const bf16x8_t*)&BsW[(t * 16 + l16) * KP + kc + quad * 8];
        }
#pragma unroll
        for (int mt = 0; mt < 4; ++mt)
#pragma unroll
            for (int t = 0; t < NT; ++t)
                acc[mt][t] = __builtin_amdgcn_mfma_f32_16x16x32_bf16(a[mt], b[t], acc[mt][t], 0, 0, 0);
    }

    // ---- epilogue: D row = quad*4 + r, col = l16 ----
#pragma unroll
    for (int mt = 0; mt < 4; ++mt) {
        int rowbase = blockIdx.x * 128 + wm * 64 + mt * 16 + quad * 4;
#pragma unroll
        for (int r = 0; r < 4; ++r) {
            int rrow = rowbase + r;
            if (rrow < M) {
                float dv = dinv[rrow];
#pragma unroll
                for (int t = 0; t < NT; ++t) {
                    int ccol = n0 + wn * (BN / 2) + t * 16 + l16;
                    Y[(size_t)rrow * NTOT + ccol] = __float2bfloat16(acc[mt][t][r] * dv);
                }
            }
        }
    }
}

// ---------------- Aggregation: out[i] = act(dinv[i]*(sum y[src] + y[i]) + b) ----------------
template<int C, bool SIG, bool OUTF32>
__global__ __launch_bounds__(256) void aggregate(
    const __hip_bfloat16* __restrict__ Y,
    const int* __restrict__ colptr,
    const int* __restrict__ esrc,
    const float* __restrict__ dinv,
    const float* __restrict__ bias,
    void* __restrict__ H,
    int M, int Etot)
{
    const int lane = threadIdx.x & 63;
    const int wave = threadIdx.x >> 6;
    int node = blockIdx.x * 4 + wave;
    if (node >= M) return;

    const unsigned short* Yp = (const unsigned short*)Y;
    int s = colptr[node];
    int e = colptr[node + 1];
    if (s < 0) s = 0;
    if (e > Etot) e = Etot;
    if (e < s) e = s;

    float a0 = 0.f, a1 = 0.f, a2 = 0.f, a3 = 0.f;

    for (int base = s; base < e; base += 64) {
        int n = e - base; if (n > 64) n = 64;
        int my = (lane < n) ? esrc[base + lane] : 0;
        if ((unsigned)my >= (unsigned)M) my = 0;
        for (int j = 0; j < n; ++j) {
            int src = __shfl(my, j);
            if constexpr (C == 256) {
                uint2 u = *(const uint2*)(Yp + (size_t)src * C + lane * 4);
                a0 += bits2f(u.x << 16);
                a1 += bits2f(u.x & 0xffff0000u);
                a2 += bits2f(u.y << 16);
                a3 += bits2f(u.y & 0xffff0000u);
            } else {
                unsigned int u = Yp[(size_t)src * C + lane];
                a0 += bits2f(u << 16);
            }
        }
    }
    // self-loop term
    if constexpr (C == 256) {
        uint2 u = *(const uint2*)(Yp + (size_t)node * C + lane * 4);
        a0 += bits2f(u.x << 16);
        a1 += bits2f(u.x & 0xffff0000u);
        a2 += bits2f(u.y << 16);
        a3 += bits2f(u.y & 0xffff0000u);
    } else {
        unsigned int u = Yp[(size_t)node * C + lane];
        a0 += bits2f(u << 16);
    }

    float dv = dinv[node];
    if constexpr (C == 256) {
        float o0 = a0 * dv + bias[lane * 4 + 0];
        float o1 = a1 * dv + bias[lane * 4 + 1];
        float o2 = a2 * dv + bias[lane * 4 + 2];
        float o3 = a3 * dv + bias[lane * 4 + 3];
        if (SIG) {
            o0 = 1.f / (1.f + __expf(-o0));
            o1 = 1.f / (1.f + __expf(-o1));
            o2 = 1.f / (1.f + __expf(-o2));
            o3 = 1.f / (1.f + __expf(-o3));
        }
        if constexpr (OUTF32) {
            float4 st = {o0, o1, o2, o3};
            *(float4*)((float*)H + (size_t)node * C + lane * 4) = st;
        } else {
            unsigned int p0 = (unsigned int)f2bf_bits(o0) | ((unsigned int)f2bf_bits(o1) << 16);
            unsigned int p1 = (unsigned int)f2bf_bits(o2) | ((unsigned int)f2bf_bits(o3) << 16);
            uint2 st; st.x = p0; st.y = p1;
            *(uint2*)((unsigned short*)H + (size_t)node * C + lane * 4) = st;
        }
    } else {
        float o = a0 * dv + bias[lane];
        if (SIG) o = 1.f / (1.f + __expf(-o));
        if constexpr (OUTF32) {
            ((float*)H)[(size_t)node * C + lane] = o;
        } else {
            ((unsigned short*)H)[(size_t)node * C + lane] = f2bf_bits(o);
        }
    }
}

// ---------------- launch ----------------

extern "C" void kernel_launch(void* const* d_in, const int* in_sizes, int n_in,
                              void* d_out, int out_size, void* d_ws, size_t ws_size,
                              hipStream_t stream)
{
    // Input order per setup_inputs(): x, edge_attr, edge_index, W1,b1,W2,b2,W3,b3.
    int iEI = 2, iW1 = 3, iB1 = 4, iW2 = 5, iB2 = 6, iW3 = 7, iB3 = 8;
    if (n_in == 8) { iEI = 1; iW1 = 2; iB1 = 3; iW2 = 4; iB2 = 5; iW3 = 6; iB3 = 7; }

    const void* x   = d_in[0];
    const int* ei   = (const int*)d_in[iEI];
    const float* W1 = (const float*)d_in[iW1];
    const float* b1 = (const float*)d_in[iB1];
    const float* W2 = (const float*)d_in[iW2];
    const float* b2 = (const float*)d_in[iB2];
    const float* W3 = (const float*)d_in[iW3];
    const float* b3 = (const float*)d_in[iB3];

    const int M = in_sizes[0] / 128;     // 50000
    const int E = in_sizes[iEI] / 2;     // 800000

    auto rnd = [](size_t b) { return (b + 255) & ~(size_t)255; };
    size_t needed = rnd(64 * 4)                          // flags
                  + rnd((size_t)M * 4) * 2               // dinv, cnt
                  + rnd((size_t)(M + 1) * 4)             // colptr
                  + rnd((size_t)M * 4)                   // cursor
                  + rnd((size_t)E * 4)                   // esrc
                  + rnd((size_t)256 * 128 * 2)           // Wt1
                  + rnd((size_t)256 * 256 * 2)           // Wt2
                  + rnd((size_t)64 * 256 * 2)            // Wt3
                  + rnd((size_t)M * 256 * 2) * 2;        // ybuf, hbuf
    if (ws_size < needed) {
        sentinel_fill<<<(out_size + 255) / 256, 256, 0, stream>>>((float*)d_out, out_size);
        return;
    }

    char* p = (char*)d_ws;
    auto alloc = [&](size_t bytes) {
        char* r = p;
        p += (bytes + 255) & ~(size_t)255;
        return r;
    };
    int* flags  = (int*)alloc(64 * 4);
    float* dinv = (float*)alloc((size_t)M * 4);
    int* cnt    = (int*)alloc((size_t)M * 4);
    int* colptr = (int*)alloc((size_t)(M + 1) * 4);
    int* cursor = (int*)alloc((size_t)M * 4);
    int* esrc   = (int*)alloc((size_t)E * 4);
    unsigned short* Wt1 = (unsigned short*)alloc((size_t)256 * 128 * 2);
    unsigned short* Wt2 = (unsigned short*)alloc((size_t)256 * 256 * 2);
    unsigned short* Wt3 = (unsigned short*)alloc((size_t)64 * 256 * 2);
    __hip_bfloat16* ybuf = (__hip_bfloat16*)alloc((size_t)M * 256 * 2);
    __hip_bfloat16* hbuf = (__hip_bfloat16*)alloc((size_t)M * 256 * 2);

    detect_ei<<<1, 64, 0, stream>>>((const unsigned int*)ei, flags);

    hipMemsetAsync(cnt, 0, (size_t)M * 4, stream);
    count_edges_dual<<<(E + 255) / 256, 256, 0, stream>>>(ei, cnt, E, M, flags);
    compute_dinv<<<(M + 255) / 256, 256, 0, stream>>>(cnt, dinv, M);
    scan_kernel<<<1, 1024, 0, stream>>>(cnt, colptr, cursor, M);
    fill_csr_dual<<<(E + 255) / 256, 256, 0, stream>>>(ei, cursor, esrc, E, M, flags);
    transpose_w<<<(128 * 256 + 255) / 256, 256, 0, stream>>>(W1, Wt1, 128, 256);
    transpose_w<<<(256 * 256 + 255) / 256, 256, 0, stream>>>(W2, Wt2, 256, 256);
    transpose_w<<<(256 * 64 + 255) / 256, 256, 0, stream>>>(W3, Wt3, 256, 64);

    int gmb = (M + 127) / 128;           // 391
    int ga  = (M + 3) / 4;
    dim3 g1(gmb, 2), g2(gmb, 2), g3(gmb, 1);
    gemm_tile<128, 128, 256, true ><<<g1, 256, 0, stream>>>(x,    Wt1, dinv, ybuf, M);
    aggregate<256, true, false><<<ga, 256, 0, stream>>>(ybuf, colptr, esrc, dinv, b1, hbuf, M, E);
    gemm_tile<256, 128, 256, false><<<g2, 256, 0, stream>>>(hbuf, Wt2, dinv, ybuf, M);
    aggregate<256, true, false><<<ga, 256, 0, stream>>>(ybuf, colptr, esrc, dinv, b2, hbuf, M, E);
    gemm_tile<256,  64,  64, false><<<g3, 256, 0, stream>>>(hbuf, Wt3, dinv, ybuf, M);
    aggregate<64, false, true><<<ga, 256, 0, stream>>>(ybuf, colptr, esrc, dinv, b3, d_out, M, E);
}

// Round 6
// 418.899 us; speedup vs baseline: 1.3278x; 1.2063x over previous
//
#include <hip/hip_runtime.h>
#include <hip/hip_bf16.h>

typedef __bf16 bf16x8_t __attribute__((ext_vector_type(8)));
typedef float f32x4_t __attribute__((ext_vector_type(4)));

__device__ __forceinline__ float bits2f(unsigned int u) {
    union { unsigned int u; float f; } c; c.u = u; return c.f;
}
__device__ __forceinline__ unsigned short f2bf_bits(float f) {
    __hip_bfloat16 h = __float2bfloat16(f);
    return __builtin_bit_cast(unsigned short, h);
}

// ---------------- sentinel (ws too small) ----------------
__global__ void sentinel_fill(float* __restrict__ out, int n) {
    int i = blockIdx.x * blockDim.x + threadIdx.x;
    if (i < n) out[i] = 100.0f;
}

// ---------------- edge_index dtype detection (int64 vs int32) ----------------
__global__ void detect_ei(const unsigned int* __restrict__ ei, int* __restrict__ flags) {
    int lane = threadIdx.x;
    int cz = 0;
    #pragma unroll
    for (int j = 0; j < 4; ++j) {
        int idx = lane * 4 + j;          // 0..255
        cz += (ei[2 * idx + 1] == 0u);   // odd words zero => int64 storage
    }
    #pragma unroll
    for (int off = 32; off; off >>= 1) cz += __shfl_down(cz, off);
    if (lane == 0) flags[0] = (cz > 200);
}

// ---------------- CSR build ----------------

__global__ void count_edges_dual(const int* __restrict__ ei, int* __restrict__ cnt,
                                 int E, int M, const int* __restrict__ flags) {
    int e = blockIdx.x * blockDim.x + threadIdx.x;
    if (e < E) {
        int c = flags[0] ? ei[2 * E + 2 * e] : ei[E + e];
        if ((unsigned)c < (unsigned)M) atomicAdd(&cnt[c], 1);
    }
}

// phase 1: per-256-block exclusive scan + block sums
__global__ void scan_blocks(const int* __restrict__ cnt, int* __restrict__ excl,
                            int* __restrict__ bsum, int n) {
    int tid = threadIdx.x;
    int i = blockIdx.x * 256 + tid;
    int lane = tid & 63, wv = tid >> 6;
    __shared__ int ws[4];
    int v = (i < n) ? cnt[i] : 0;
    int s = v;
    #pragma unroll
    for (int off = 1; off < 64; off <<= 1) {
        int t = __shfl_up(s, off);
        if (lane >= off) s += t;
    }
    if (lane == 63) ws[wv] = s;
    __syncthreads();
    if (tid == 0) { int a = 0; for (int q = 0; q < 4; ++q) { int t = ws[q]; ws[q] = a; a += t; } }
    __syncthreads();
    int ex = s - v + ws[wv];
    if (i < n) excl[i] = ex;
    if (tid == 255) bsum[blockIdx.x] = ex + v;
}

// phase 2: single-block scan of block sums (+ writes colptr[n] total)
__global__ void scan_bsums(const int* __restrict__ bsum, int* __restrict__ boff,
                           int nb, int* __restrict__ colptr, int n) {
    int tid = threadIdx.x, lane = tid & 63, wv = tid >> 6;
    __shared__ int ws[4];
    __shared__ int carry;
    if (tid == 0) carry = 0;
    __syncthreads();
    for (int base = 0; base < nb; base += 256) {
        int i = base + tid;
        int v = (i < nb) ? bsum[i] : 0;
        int s = v;
        #pragma unroll
        for (int off = 1; off < 64; off <<= 1) {
            int t = __shfl_up(s, off);
            if (lane >= off) s += t;
        }
        if (lane == 63) ws[wv] = s;
        __syncthreads();
        if (tid == 0) { int a = carry; for (int q = 0; q < 4; ++q) { int t = ws[q]; ws[q] = a; a += t; } carry = a; }
        __syncthreads();
        int ex = s - v + ws[wv];
        if (i < nb) boff[i] = ex;
        __syncthreads();
    }
    if (tid == 0) colptr[n] = carry;
}

// phase 3: add block offsets; also compute dinv
__global__ void scan_add_dinv(const int* __restrict__ excl, const int* __restrict__ boff,
                              const int* __restrict__ cnt, int* __restrict__ colptr,
                              int* __restrict__ cursor, float* __restrict__ dinv, int n) {
    int i = blockIdx.x * 256 + threadIdx.x;
    if (i < n) {
        int v = excl[i] + boff[blockIdx.x];
        colptr[i] = v;
        cursor[i] = v;
        dinv[i] = rsqrtf((float)cnt[i] + 1.0f);
    }
}

__global__ void fill_csr_dual(const int* __restrict__ ei, int* __restrict__ cursor,
                              int* __restrict__ esrc, int E, int M,
                              const int* __restrict__ flags) {
    int e = blockIdx.x * blockDim.x + threadIdx.x;
    if (e < E) {
        int r, c;
        if (flags[0]) { r = ei[2 * e]; c = ei[2 * E + 2 * e]; }
        else          { r = ei[e];     c = ei[E + e]; }
        if ((unsigned)c < (unsigned)M && (unsigned)r < (unsigned)M) {
            int p = atomicAdd(&cursor[c], 1);
            if ((unsigned)p < (unsigned)E) esrc[p] = r;
        }
    }
}

// ---------------- fused weight transposes f32 -> bf16 (W^T layout) ----------------
__global__ void transpose_all(const float* __restrict__ W1, const float* __restrict__ W2,
                              const float* __restrict__ W3,
                              unsigned short* __restrict__ Wt1, unsigned short* __restrict__ Wt2,
                              unsigned short* __restrict__ Wt3) {
    int i = blockIdx.x * 256 + threadIdx.x;
    if (i < 32768) {                       // W1: 128x256
        int k = i >> 8, n = i & 255;
        Wt1[n * 128 + k] = f2bf_bits(W1[i]);
    } else if (i < 32768 + 65536) {        // W2: 256x256
        int j = i - 32768;
        int k = j >> 8, n = j & 255;
        Wt2[n * 256 + k] = f2bf_bits(W2[j]);
    } else if (i < 114688) {               // W3: 256x64
        int j = i - 98304;
        int k = j >> 6, n = j & 63;
        Wt3[n * 256 + k] = f2bf_bits(W3[j]);
    }
}

// ---------------- tiled GEMM + dinv scale (bf16 MFMA) ----------------
// Y[m][n0+n] = dinv[m] * sum_k A[m][k] * Bt[n0+n][k]
// Block: 4 waves (2x2) over a 128 x BN tile; wave tile 64 x (BN/2).
template<int K, int BN, int NTOT, bool AF32>
__global__ __launch_bounds__(256) void gemm_tile(
    const void* __restrict__ A,
    const unsigned short* __restrict__ Bt,
    const float* __restrict__ dinv,
    __hip_bfloat16* __restrict__ Y,
    int M)
{
    constexpr int KP = K + 8;
    constexpr int NT = BN / 2 / 16;   // n-tiles per wave
    __shared__ unsigned short Bs[BN * KP];

    const int tid  = threadIdx.x;
    const int lane = tid & 63;
    const int wave = tid >> 6;        // 0..3
    const int wm   = wave >> 1;       // 0..1  row group
    const int wn   = wave & 1;        // 0..1  col group
    const int quad = lane >> 4;       // 0..3
    const int l16  = lane & 15;
    const int n0   = blockIdx.y * BN;

    // ---- stage B tile into LDS (one shot) ----
    constexpr int CH = BN * K / 8;    // 16B chunks
    for (int idx = tid; idx < CH; idx += 256) {
        int n  = idx / (K / 8);
        int k8 = idx - n * (K / 8);
        uint4 v = *(const uint4*)(Bt + (size_t)(n0 + n) * K + k8 * 8);
        *(uint4*)&Bs[n * KP + k8 * 8] = v;
    }
    __syncthreads();

    int mrow[4];
#pragma unroll
    for (int mt = 0; mt < 4; ++mt) {
        int r = blockIdx.x * 128 + wm * 64 + mt * 16 + l16;
        mrow[mt] = (r < M) ? r : (M - 1);
    }

    f32x4_t acc[4][NT];
#pragma unroll
    for (int mt = 0; mt < 4; ++mt)
#pragma unroll
        for (int t = 0; t < NT; ++t) acc[mt][t] = (f32x4_t){0.f, 0.f, 0.f, 0.f};

    const unsigned short* BsW = &Bs[(wn * (BN / 2)) * KP];

#pragma unroll
    for (int kc = 0; kc < K; kc += 32) {
        bf16x8_t a[4], b[NT];
#pragma unroll
        for (int mt = 0; mt < 4; ++mt) {
            if constexpr (AF32) {
                const float* Af = (const float*)A + (size_t)mrow[mt] * K + kc + quad * 8;
                float4 f0 = *(const float4*)(Af);
                float4 f1 = *(const float4*)(Af + 4);
                a[mt] = (bf16x8_t){(__bf16)f0.x, (__bf16)f0.y, (__bf16)f0.z, (__bf16)f0.w,
                                   (__bf16)f1.x, (__bf16)f1.y, (__bf16)f1.z, (__bf16)f1.w};
            } else {
                a[mt] = *(const bf16x8_t*)((const __bf16*)A + (size_t)mrow[mt] * K + kc + quad * 8);
            }
        }
#pragma unroll
        for (int t = 0; t < NT; ++t) {
            b[t] = *(const bf16x8_t*)&BsW[(t * 16 + l16) * KP + kc + quad * 8];
        }
#pragma unroll
        for (int mt = 0; mt < 4; ++mt)
#pragma unroll
            for (int t = 0; t < NT; ++t)
                acc[mt][t] = __builtin_amdgcn_mfma_f32_16x16x32_bf16(a[mt], b[t], acc[mt][t], 0, 0, 0);
    }

#pragma unroll
    for (int mt = 0; mt < 4; ++mt) {
        int rowbase = blockIdx.x * 128 + wm * 64 + mt * 16 + quad * 4;
#pragma unroll
        for (int r = 0; r < 4; ++r) {
            int rrow = rowbase + r;
            if (rrow < M) {
                float dv = dinv[rrow];
#pragma unroll
                for (int t = 0; t < NT; ++t) {
                    int ccol = n0 + wn * (BN / 2) + t * 16 + l16;
                    Y[(size_t)rrow * NTOT + ccol] = __float2bfloat16(acc[mt][t][r] * dv);
                }
            }
        }
    }
}

// ---------------- Aggregation: out[i] = act(dinv[i]*(sum y[src] + y[i]) + b) ----------------
// Lane-group gather: G = C/8 lanes per 16B-strided row, EPW = 64/G edges in flight.
template<int C, bool SIG, bool OUTF32>
__global__ __launch_bounds__(256) void aggregate(
    const __hip_bfloat16* __restrict__ Y,
    const int* __restrict__ colptr,
    const int* __restrict__ esrc,
    const float* __restrict__ dinv,
    const float* __restrict__ bias,
    void* __restrict__ H,
    int M, int Etot)
{
    constexpr int G   = C / 8;       // lanes per edge row (256->32, 64->8)
    constexpr int EPW = 64 / G;      // edges in flight     (2 / 8)
    const int lane = threadIdx.x & 63;
    const int wave = threadIdx.x >> 6;
    const int l = lane & (G - 1);
    const int g = lane / G;
    int node = blockIdx.x * 4 + wave;
    if (node >= M) return;

    const unsigned short* Yp = (const unsigned short*)Y;
    int s = colptr[node];
    int e = colptr[node + 1];
    if (s < 0) s = 0;
    if (e > Etot) e = Etot;
    if (e < s) e = s;

    float acc[8];
    #pragma unroll
    for (int k = 0; k < 8; ++k) acc[k] = 0.f;

    for (int base = s; base < e; base += 64) {
        int n = e - base; if (n > 64) n = 64;
        int my = (lane < n) ? esrc[base + lane] : 0;
        if ((unsigned)my >= (unsigned)M) my = 0;
        for (int j = 0; j < n; j += EPW) {
            int idx = j + g;
            int src = __shfl(my, idx);
            if (idx < n) {
                uint4 u = *(const uint4*)(Yp + (size_t)src * C + l * 8);
                acc[0] += bits2f(u.x << 16);
                acc[1] += bits2f(u.x & 0xffff0000u);
                acc[2] += bits2f(u.y << 16);
                acc[3] += bits2f(u.y & 0xffff0000u);
                acc[4] += bits2f(u.z << 16);
                acc[5] += bits2f(u.z & 0xffff0000u);
                acc[6] += bits2f(u.w << 16);
                acc[7] += bits2f(u.w & 0xffff0000u);
            }
        }
    }
    // self-loop term (group 0 only, so it's counted once)
    if (g == 0) {
        uint4 u = *(const uint4*)(Yp + (size_t)node * C + l * 8);
        acc[0] += bits2f(u.x << 16);
        acc[1] += bits2f(u.x & 0xffff0000u);
        acc[2] += bits2f(u.y << 16);
        acc[3] += bits2f(u.y & 0xffff0000u);
        acc[4] += bits2f(u.z << 16);
        acc[5] += bits2f(u.z & 0xffff0000u);
        acc[6] += bits2f(u.w << 16);
        acc[7] += bits2f(u.w & 0xffff0000u);
    }
    // cross-group reduction
    #pragma unroll
    for (int off = G; off < 64; off <<= 1) {
        #pragma unroll
        for (int k = 0; k < 8; ++k) acc[k] += __shfl_xor(acc[k], off);
    }

    if (g == 0) {   // lanes [0,G) hold channels [l*8, l*8+8)
        float dv = dinv[node];
        float o[8];
        #pragma unroll
        for (int k = 0; k < 8; ++k) {
            o[k] = acc[k] * dv + bias[l * 8 + k];
            if (SIG) o[k] = 1.f / (1.f + __expf(-o[k]));
        }
        if constexpr (OUTF32) {
            float* Hp = (float*)H + (size_t)node * C + l * 8;
            *(float4*)Hp       = (float4){o[0], o[1], o[2], o[3]};
            *(float4*)(Hp + 4) = (float4){o[4], o[5], o[6], o[7]};
        } else {
            uint4 st;
            st.x = (unsigned int)f2bf_bits(o[0]) | ((unsigned int)f2bf_bits(o[1]) << 16);
            st.y = (unsigned int)f2bf_bits(o[2]) | ((unsigned int)f2bf_bits(o[3]) << 16);
            st.z = (unsigned int)f2bf_bits(o[4]) | ((unsigned int)f2bf_bits(o[5]) << 16);
            st.w = (unsigned int)f2bf_bits(o[6]) | ((unsigned int)f2bf_bits(o[7]) << 16);
            *(uint4*)((unsigned short*)H + (size_t)node * C + l * 8) = st;
        }
    }
}

// ---------------- launch ----------------

extern "C" void kernel_launch(void* const* d_in, const int* in_sizes, int n_in,
                              void* d_out, int out_size, void* d_ws, size_t ws_size,
                              hipStream_t stream)
{
    int iEI = 2, iW1 = 3, iB1 = 4, iW2 = 5, iB2 = 6, iW3 = 7, iB3 = 8;
    if (n_in == 8) { iEI = 1; iW1 = 2; iB1 = 3; iW2 = 4; iB2 = 5; iW3 = 6; iB3 = 7; }

    const void* x   = d_in[0];
    const int* ei   = (const int*)d_in[iEI];
    const float* W1 = (const float*)d_in[iW1];
    const float* b1 = (const float*)d_in[iB1];
    const float* W2 = (const float*)d_in[iW2];
    const float* b2 = (const float*)d_in[iB2];
    const float* W3 = (const float*)d_in[iW3];
    const float* b3 = (const float*)d_in[iB3];

    const int M = in_sizes[0] / 128;     // 50000
    const int E = in_sizes[iEI] / 2;     // 800000
    const int NB = (M + 255) / 256;      // scan blocks

    auto rnd = [](size_t b) { return (b + 255) & ~(size_t)255; };
    size_t needed = rnd(64 * 4)                          // flags
                  + rnd((size_t)M * 4) * 2               // dinv, cnt
                  + rnd((size_t)(M + 1) * 4)             // colptr
                  + rnd((size_t)M * 4)                   // cursor
                  + rnd((size_t)M * 4)                   // excl
                  + rnd((size_t)(NB + 1) * 4) * 2        // bsum, boff
                  + rnd((size_t)E * 4)                   // esrc
                  + rnd((size_t)256 * 128 * 2)           // Wt1
                  + rnd((size_t)256 * 256 * 2)           // Wt2
                  + rnd((size_t)64 * 256 * 2)            // Wt3
                  + rnd((size_t)M * 256 * 2) * 2;        // ybuf, hbuf
    if (ws_size < needed) {
        sentinel_fill<<<(out_size + 255) / 256, 256, 0, stream>>>((float*)d_out, out_size);
        return;
    }

    char* p = (char*)d_ws;
    auto alloc = [&](size_t bytes) {
        char* r = p;
        p += (bytes + 255) & ~(size_t)255;
        return r;
    };
    int* flags  = (int*)alloc(64 * 4);
    float* dinv = (float*)alloc((size_t)M * 4);
    int* cnt    = (int*)alloc((size_t)M * 4);
    int* colptr = (int*)alloc((size_t)(M + 1) * 4);
    int* cursor = (int*)alloc((size_t)M * 4);
    int* excl   = (int*)alloc((size_t)M * 4);
    int* bsum   = (int*)alloc((size_t)(NB + 1) * 4);
    int* boff   = (int*)alloc((size_t)(NB + 1) * 4);
    int* esrc   = (int*)alloc((size_t)E * 4);
    unsigned short* Wt1 = (unsigned short*)alloc((size_t)256 * 128 * 2);
    unsigned short* Wt2 = (unsigned short*)alloc((size_t)256 * 256 * 2);
    unsigned short* Wt3 = (unsigned short*)alloc((size_t)64 * 256 * 2);
    __hip_bfloat16* ybuf = (__hip_bfloat16*)alloc((size_t)M * 256 * 2);
    __hip_bfloat16* hbuf = (__hip_bfloat16*)alloc((size_t)M * 256 * 2);

    detect_ei<<<1, 64, 0, stream>>>((const unsigned int*)ei, flags);

    hipMemsetAsync(cnt, 0, (size_t)M * 4, stream);
    count_edges_dual<<<(E + 255) / 256, 256, 0, stream>>>(ei, cnt, E, M, flags);
    scan_blocks<<<NB, 256, 0, stream>>>(cnt, excl, bsum, M);
    scan_bsums<<<1, 256, 0, stream>>>(bsum, boff, NB, colptr, M);
    scan_add_dinv<<<NB, 256, 0, stream>>>(excl, boff, cnt, colptr, cursor, dinv, M);
    fill_csr_dual<<<(E + 255) / 256, 256, 0, stream>>>(ei, cursor, esrc, E, M, flags);
    transpose_all<<<(114688 + 255) / 256, 256, 0, stream>>>(W1, W2, W3, Wt1, Wt2, Wt3);

    int gmb = (M + 127) / 128;           // 391
    int ga  = (M + 3) / 4;
    dim3 g1(gmb, 2), g2(gmb, 2), g3(gmb, 1);
    gemm_tile<128, 128, 256, true ><<<g1, 256, 0, stream>>>(x,    Wt1, dinv, ybuf, M);
    aggregate<256, true, false><<<ga, 256, 0, stream>>>(ybuf, colptr, esrc, dinv, b1, hbuf, M, E);
    gemm_tile<256, 128, 256, false><<<g2, 256, 0, stream>>>(hbuf, Wt2, dinv, ybuf, M);
    aggregate<256, true, false><<<ga, 256, 0, stream>>>(ybuf, colptr, esrc, dinv, b2, hbuf, M, E);
    gemm_tile<256,  64,  64, false><<<g3, 256, 0, stream>>>(hbuf, Wt3, dinv, ybuf, M);
    aggregate<64, false, true><<<ga, 256, 0, stream>>>(ybuf, colptr, esrc, dinv, b3, d_out, M, E);
}